// Round 14
// baseline (355.735 us; speedup 1.0000x reference)
//
#include <hip/hip_runtime.h>
#include <math.h>

#define BB 2
#define TT 2048
#define DD 1024
#define HH 16
#define DH 64
#define BTOT (BB*TT)
#define NEG_INF (-1e30f)

typedef _Float16 half8 __attribute__((ext_vector_type(8)));
typedef _Float16 half4 __attribute__((ext_vector_type(4)));
typedef float floatx4 __attribute__((ext_vector_type(4)));

// ---------------- split fp32 -> fp16 hi/lo (elementwise) ----------------
__global__ __launch_bounds__(256) void split_f32(const float* __restrict__ in,
                                                 _Float16* __restrict__ hi,
                                                 _Float16* __restrict__ lo,
                                                 int n4) {
  int idx = blockIdx.x * 256 + threadIdx.x;
  const int stride = gridDim.x * 256;
  for (; idx < n4; idx += stride) {
    float4 v = reinterpret_cast<const float4*>(in)[idx];
    half4 hv, lv;
    hv[0] = (_Float16)v.x; lv[0] = (_Float16)(v.x - (float)hv[0]);
    hv[1] = (_Float16)v.y; lv[1] = (_Float16)(v.y - (float)hv[1]);
    hv[2] = (_Float16)v.z; lv[2] = (_Float16)(v.z - (float)hv[2]);
    hv[3] = (_Float16)v.w; lv[3] = (_Float16)(v.w - (float)hv[3]);
    reinterpret_cast<half4*>(hi)[idx] = hv;
    reinterpret_cast<half4*>(lo)[idx] = lv;
  }
}

// ---------------- transpose + split: W[K][N] fp32 -> Wt_hi/lo[N][K] fp16 ----------------
__global__ __launch_bounds__(256) void wsplit_t(const float* __restrict__ W,
                                                _Float16* __restrict__ Wth,
                                                _Float16* __restrict__ Wtl,
                                                int K, int N) {
  __shared__ float buf[64][65];
  const int tid = threadIdx.x;
  const int k0 = blockIdx.y * 64;
  const int n0 = blockIdx.x * 64;
  const int rr = tid >> 4;          // 0..15
  const int cc = (tid & 15) * 4;    // 0..60
#pragma unroll
  for (int p = 0; p < 4; ++p) {
    const int r = rr + p * 16;
    float4 v = *reinterpret_cast<const float4*>(&W[(size_t)(k0 + r) * N + n0 + cc]);
    buf[r][cc+0] = v.x; buf[r][cc+1] = v.y; buf[r][cc+2] = v.z; buf[r][cc+3] = v.w;
  }
  __syncthreads();
  const int tn = tid >> 2;
#pragma unroll
  for (int pp = 0; pp < 2; ++pp) {
    const int c2 = (tid & 3) + pp * 4;
    half8 hv, lv;
#pragma unroll
    for (int j = 0; j < 8; ++j) {
      float f = buf[c2*8 + j][tn];
      hv[j] = (_Float16)f;
      lv[j] = (_Float16)(f - (float)hv[j]);
    }
    *reinterpret_cast<half8*>(&Wth[(size_t)(n0 + tn) * K + k0 + c2*8]) = hv;
    *reinterpret_cast<half8*>(&Wtl[(size_t)(n0 + tn) * K + k0 + c2*8]) = lv;
  }
}

// ---------------- router: logits -> softmax probs -> top-4 gate ----------------
__global__ __launch_bounds__(64) void router_kernel(const float* __restrict__ x,
                                                    const float* __restrict__ Wr,
                                                    float* __restrict__ gates) {
  const int row = blockIdx.x;
  const int lane = threadIdx.x;
  const float* xr = x + (size_t)row * DD;
  float acc[16];
#pragma unroll
  for (int c = 0; c < 16; ++c) acc[c] = 0.f;
  for (int d = lane; d < DD; d += 64) {
    float xv = xr[d];
    const float4* wrow = reinterpret_cast<const float4*>(Wr + (size_t)d * HH);
#pragma unroll
    for (int g = 0; g < 4; ++g) {
      float4 w = wrow[g];
      acc[g*4+0] = fmaf(xv, w.x, acc[g*4+0]);
      acc[g*4+1] = fmaf(xv, w.y, acc[g*4+1]);
      acc[g*4+2] = fmaf(xv, w.z, acc[g*4+2]);
      acc[g*4+3] = fmaf(xv, w.w, acc[g*4+3]);
    }
  }
#pragma unroll
  for (int c = 0; c < 16; ++c) {
    float v = acc[c];
    v += __shfl_down(v, 32);
    v += __shfl_down(v, 16);
    v += __shfl_down(v, 8);
    v += __shfl_down(v, 4);
    v += __shfl_down(v, 2);
    v += __shfl_down(v, 1);
    acc[c] = v;
  }
  if (lane == 0) {
    float mx = acc[0];
#pragma unroll
    for (int c = 1; c < 16; ++c) mx = fmaxf(mx, acc[c]);
    float e[16]; float den = 0.f;
#pragma unroll
    for (int c = 0; c < 16; ++c) { e[c] = __expf(acc[c] - mx); den += e[c]; }
    float tmp[16];
#pragma unroll
    for (int c = 0; c < 16; ++c) tmp[c] = acc[c];
    float th = NEG_INF;
    for (int it = 0; it < 4; ++it) {
      float bv = NEG_INF; int bi = 0;
      for (int c = 0; c < 16; ++c) { if (tmp[c] > bv) { bv = tmp[c]; bi = c; } }
      tmp[bi] = NEG_INF;
      th = bv;
    }
    float inv = 1.f / den;
    float* gr = gates + (size_t)row * HH;
#pragma unroll
    for (int c = 0; c < 16; ++c) gr[c] = (acc[c] >= th) ? e[c] * inv : 0.f;
  }
}

// ---------------- split-fp16 MFMA GEMM ----------------
// C(MxN) = A(MxK) @ B(KxN), A as hi/lo fp16 [M][K], B^T as hi/lo fp16 [N][K].
// acc += Ah*Bh + Ah*Bl + Al*Bh. 128x128 tile, BK=32, 4 waves, 4x4 16x16x32 frags.
// EMIT_HALF=true: epilogue emits fp16 hi/lo planes (Ch,Cl) instead of fp32 C.
template<bool EMIT_HALF>
__global__ __launch_bounds__(256) void hgemm_split(const _Float16* __restrict__ Ah,
                                                   const _Float16* __restrict__ Al,
                                                   const _Float16* __restrict__ Bth,
                                                   const _Float16* __restrict__ Btl,
                                                   float* __restrict__ C,
                                                   _Float16* __restrict__ Ch,
                                                   _Float16* __restrict__ Cl,
                                                   int M, int N, int K) {
  __shared__ _Float16 As[2][128][40];  // [hi/lo][m][k], rows padded to 40 (80B)
  __shared__ _Float16 Bs[2][128][40];  // [hi/lo][n][k]
  const int tid = threadIdx.x;
  const int lane = tid & 63;
  const int w = tid >> 6;
  const int wr = w >> 1, wc = w & 1;
  const int lr = lane & 15, lg = lane >> 4;
  const int m0 = blockIdx.y * 128, n0 = blockIdx.x * 128;
  const int srow = tid >> 2;        // 0..63
  const int schunk = (tid & 3) * 8; // halves offset: 0,8,16,24
  const _Float16* ApH = Ah + (size_t)(m0 + srow) * K + schunk;
  const _Float16* ApL = Al + (size_t)(m0 + srow) * K + schunk;
  const _Float16* BpH = Bth + (size_t)(n0 + srow) * K + schunk;
  const _Float16* BpL = Btl + (size_t)(n0 + srow) * K + schunk;
  const size_t rskip = (size_t)64 * K;

  floatx4 acc[4][4] = {};
  for (int k0 = 0; k0 < K; k0 += 32) {
    int4 a0h = *reinterpret_cast<const int4*>(ApH + k0);
    int4 a1h = *reinterpret_cast<const int4*>(ApH + rskip + k0);
    int4 a0l = *reinterpret_cast<const int4*>(ApL + k0);
    int4 a1l = *reinterpret_cast<const int4*>(ApL + rskip + k0);
    int4 b0h = *reinterpret_cast<const int4*>(BpH + k0);
    int4 b1h = *reinterpret_cast<const int4*>(BpH + rskip + k0);
    int4 b0l = *reinterpret_cast<const int4*>(BpL + k0);
    int4 b1l = *reinterpret_cast<const int4*>(BpL + rskip + k0);
    __syncthreads();   // previous iter's LDS reads complete
    *reinterpret_cast<int4*>(&As[0][srow][schunk])      = a0h;
    *reinterpret_cast<int4*>(&As[0][srow + 64][schunk]) = a1h;
    *reinterpret_cast<int4*>(&As[1][srow][schunk])      = a0l;
    *reinterpret_cast<int4*>(&As[1][srow + 64][schunk]) = a1l;
    *reinterpret_cast<int4*>(&Bs[0][srow][schunk])      = b0h;
    *reinterpret_cast<int4*>(&Bs[0][srow + 64][schunk]) = b1h;
    *reinterpret_cast<int4*>(&Bs[1][srow][schunk])      = b0l;
    *reinterpret_cast<int4*>(&Bs[1][srow + 64][schunk]) = b1l;
    __syncthreads();
    half8 af[2][4], bf[2][4];
#pragma unroll
    for (int mi = 0; mi < 4; ++mi) {
      af[0][mi] = *reinterpret_cast<const half8*>(&As[0][wr*64 + mi*16 + lr][lg*8]);
      af[1][mi] = *reinterpret_cast<const half8*>(&As[1][wr*64 + mi*16 + lr][lg*8]);
    }
#pragma unroll
    for (int ni = 0; ni < 4; ++ni) {
      bf[0][ni] = *reinterpret_cast<const half8*>(&Bs[0][wc*64 + ni*16 + lr][lg*8]);
      bf[1][ni] = *reinterpret_cast<const half8*>(&Bs[1][wc*64 + ni*16 + lr][lg*8]);
    }
#pragma unroll
    for (int mi = 0; mi < 4; ++mi)
#pragma unroll
      for (int ni = 0; ni < 4; ++ni) {
        acc[mi][ni] = __builtin_amdgcn_mfma_f32_16x16x32_f16(af[0][mi], bf[0][ni], acc[mi][ni], 0, 0, 0);
        acc[mi][ni] = __builtin_amdgcn_mfma_f32_16x16x32_f16(af[0][mi], bf[1][ni], acc[mi][ni], 0, 0, 0);
        acc[mi][ni] = __builtin_amdgcn_mfma_f32_16x16x32_f16(af[1][mi], bf[0][ni], acc[mi][ni], 0, 0, 0);
      }
  }
  // C/D layout: col = lane&15, row = (lane>>4)*4 + reg (m89-verified)
#pragma unroll
  for (int mi = 0; mi < 4; ++mi)
#pragma unroll
    for (int ni = 0; ni < 4; ++ni) {
      const int n = n0 + wc*64 + ni*16 + lr;
#pragma unroll
      for (int r = 0; r < 4; ++r) {
        const int m = m0 + wr*64 + mi*16 + lg*4 + r;
        const float v = acc[mi][ni][r];
        if (EMIT_HALF) {
          const _Float16 vh = (_Float16)v;
          Ch[(size_t)m * N + n] = vh;
          Cl[(size_t)m * N + n] = (_Float16)(v - (float)vh);
        } else {
          C[(size_t)m * N + n] = v;
        }
      }
    }
}

// ---------------- MFMA flash attention, QBLK=128, 8 waves ----------------
// 8 waves/block (512 thr); wave wv owns Q rows qt*128+wv*16..+15 (frags in reg).
// One 64-key K/V stage + barrier pair serves 128 Q-rows (2x amortization vs
// QBLK=64). K staged [n][d] hi/lo; V^T [d][n] hi-only; P hi/lo in the wave's
// own LDS rows (same-wave RAW -> no extra barrier). Waves fully masked for a
// diagonal tile skip compute (wave-uniform branch, after the barrier pair).
__global__ __launch_bounds__(512) void attn_mfma(const _Float16* __restrict__ qkvh,
                                                 const _Float16* __restrict__ qkvl,
                                                 const float* __restrict__ gates,
                                                 _Float16* __restrict__ yhi,
                                                 _Float16* __restrict__ ylo) {
  __shared__ _Float16 Ksh[64][68], Ksl[64][68];   // K: [n][d]
  __shared__ _Float16 Vth[64][68];                // V^T: [d][n] (hi)
  __shared__ _Float16 Psh[128][68], Psl[128][68]; // P: [m][n], 128 q-rows
  const int nQT = TT / 128;
  const int bid = blockIdx.x;
  const int qt = nQT - 1 - bid / (BB*HH);   // longest blocks first
  const int bh = bid % (BB*HH);
  const int b = bh / HH, h = bh % HH;
  const int tid = threadIdx.x;
  const int lane = tid & 63;
  const int wv = tid >> 6;          // 0..7
  const int lr = lane & 15;
  const int lg = lane >> 4;
  const size_t rs = 3 * DD;
  const _Float16* kbh = qkvh + (size_t)b*TT*rs + DD + h*DH;
  const _Float16* kbl = qkvl + (size_t)b*TT*rs + DD + h*DH;
  const _Float16* vbh = qkvh + (size_t)b*TT*rs + 2*DD + h*DH;

  // Q fragments hi/lo: row = qt*128+wv*16+lr, k = c*32 + lg*8 + j
  half8 qfh[2], qfl[2];
  {
    const _Float16* qrh = qkvh + (size_t)(b*TT + qt*128 + wv*16 + lr) * rs + h*DH + lg*8;
    const _Float16* qrl = qkvl + (size_t)(b*TT + qt*128 + wv*16 + lr) * rs + h*DH + lg*8;
#pragma unroll
    for (int c = 0; c < 2; ++c) {
      qfh[c] = *reinterpret_cast<const half8*>(qrh + c*32);
      qfl[c] = *reinterpret_cast<const half8*>(qrl + c*32);
    }
  }
  floatx4 oacc[4] = {};   // [dfrag]; row m=lg*4+r, col d=dfrag*16+lr
  float rowM[4], rowL[4];
#pragma unroll
  for (int r = 0; r < 4; ++r) { rowM[r] = NEG_INF; rowL[r] = 0.f; }

  const int sm = tid >> 3;          // staging row 0..63
  const int sg = tid & 7;           // staging chunk (8 halves)
  const int wmax = qt*128 + wv*16 + 15;   // this wave's last q-row
  const int jmax = 2*qt + 1;

  for (int jt = 0; jt <= jmax; ++jt) {
    const size_t roff = (size_t)(jt*64 + sm) * rs + sg*8;
    half8 kh = *reinterpret_cast<const half8*>(kbh + roff);
    half8 kl = *reinterpret_cast<const half8*>(kbl + roff);
    half8 vh = *reinterpret_cast<const half8*>(vbh + roff);
    __syncthreads();   // prior iter's frag reads complete
    *reinterpret_cast<half8*>(&Ksh[sm][sg*8]) = kh;
    *reinterpret_cast<half8*>(&Ksl[sm][sg*8]) = kl;
#pragma unroll
    for (int jj = 0; jj < 8; ++jj)
      Vth[sg*8 + jj][sm] = vh[jj];
    __syncthreads();
    if (jt*64 > wmax) continue;   // wave fully masked (wave-uniform)
    // S = Q K^T  (3-term split)
    floatx4 sacc[4] = {};
#pragma unroll
    for (int c = 0; c < 2; ++c)
#pragma unroll
      for (int nf = 0; nf < 4; ++nf) {
        half8 kfh = *reinterpret_cast<const half8*>(&Ksh[nf*16 + lr][c*32 + lg*8]);
        half8 kfl = *reinterpret_cast<const half8*>(&Ksl[nf*16 + lr][c*32 + lg*8]);
        sacc[nf] = __builtin_amdgcn_mfma_f32_16x16x32_f16(qfh[c], kfh, sacc[nf], 0, 0, 0);
        sacc[nf] = __builtin_amdgcn_mfma_f32_16x16x32_f16(qfh[c], kfl, sacc[nf], 0, 0, 0);
        sacc[nf] = __builtin_amdgcn_mfma_f32_16x16x32_f16(qfl[c], kfh, sacc[nf], 0, 0, 0);
      }
    // online softmax in C/D layout (row replicated across the 16 lr-lanes)
    float p[4][4];   // [nf][r]
    float corr[4];
#pragma unroll
    for (int r = 0; r < 4; ++r) {
      const int qidx = qt*128 + wv*16 + lg*4 + r;
      float tmax = NEG_INF;
#pragma unroll
      for (int nf = 0; nf < 4; ++nf) {
        const int kidx = jt*64 + nf*16 + lr;
        float sv = sacc[nf][r] * 0.125f;
        if (kidx > qidx) sv = NEG_INF;
        p[nf][r] = sv;
        tmax = fmaxf(tmax, sv);
      }
      tmax = fmaxf(tmax, __shfl_xor(tmax, 1));
      tmax = fmaxf(tmax, __shfl_xor(tmax, 2));
      tmax = fmaxf(tmax, __shfl_xor(tmax, 4));
      tmax = fmaxf(tmax, __shfl_xor(tmax, 8));
      const float mnew = fmaxf(rowM[r], tmax);
      corr[r] = __expf(rowM[r] - mnew);
      float tsum = 0.f;
#pragma unroll
      for (int nf = 0; nf < 4; ++nf) {
        const float pv = __expf(p[nf][r] - mnew);
        p[nf][r] = pv;
        tsum += pv;
      }
      tsum += __shfl_xor(tsum, 1);
      tsum += __shfl_xor(tsum, 2);
      tsum += __shfl_xor(tsum, 4);
      tsum += __shfl_xor(tsum, 8);
      rowL[r] = rowL[r] * corr[r] + tsum;
      rowM[r] = mnew;
    }
    // P -> LDS (hi/lo), this wave's rows only
#pragma unroll
    for (int nf = 0; nf < 4; ++nf)
#pragma unroll
      for (int r = 0; r < 4; ++r) {
        const _Float16 ph = (_Float16)p[nf][r];
        Psh[wv*16 + lg*4 + r][nf*16 + lr] = ph;
        Psl[wv*16 + lg*4 + r][nf*16 + lr] = (_Float16)(p[nf][r] - (float)ph);
      }
    // rescale O
#pragma unroll
    for (int df = 0; df < 4; ++df)
#pragma unroll
      for (int r = 0; r < 4; ++r)
        oacc[df][r] *= corr[r];
    // O += P V (P hi/lo x V hi)
#pragma unroll
    for (int c = 0; c < 2; ++c) {
      half8 pah = *reinterpret_cast<const half8*>(&Psh[wv*16 + lr][c*32 + lg*8]);
      half8 pal = *reinterpret_cast<const half8*>(&Psl[wv*16 + lr][c*32 + lg*8]);
#pragma unroll
      for (int df = 0; df < 4; ++df) {
        half8 vfh = *reinterpret_cast<const half8*>(&Vth[df*16 + lr][c*32 + lg*8]);
        oacc[df] = __builtin_amdgcn_mfma_f32_16x16x32_f16(pah, vfh, oacc[df], 0, 0, 0);
        oacc[df] = __builtin_amdgcn_mfma_f32_16x16x32_f16(pal, vfh, oacc[df], 0, 0, 0);
      }
    }
  }
  // epilogue: normalize + gate, emit fp16 hi/lo split of ypre
#pragma unroll
  for (int r = 0; r < 4; ++r) {
    const int t = qt*128 + wv*16 + lg*4 + r;
    const float g = gates[((size_t)(b*TT + t)) * HH + h];
    const float sc = g / rowL[r];
#pragma unroll
    for (int df = 0; df < 4; ++df) {
      const float v = oacc[df][r] * sc;
      const _Float16 vh = (_Float16)v;
      const size_t off = ((size_t)(b*TT + t)) * DD + h*DH + df*16 + lr;
      yhi[off] = vh;
      ylo[off] = (_Float16)(v - (float)vh);
    }
  }
}

extern "C" void kernel_launch(void* const* d_in, const int* in_sizes, int n_in,
                              void* d_out, int out_size, void* d_ws, size_t ws_size,
                              hipStream_t stream) {
  (void)in_sizes; (void)n_in; (void)out_size; (void)ws_size;
  const float* x    = (const float*)d_in[0];
  const float* Wqkv = (const float*)d_in[1];
  const float* Wr   = (const float*)d_in[2];
  const float* Wo   = (const float*)d_in[3];
  float* out = (float*)d_out;

  _Float16* qkvh = (_Float16*)d_ws;                 // [BTOT][3*DD] fp16 hi (25.2 MB)
  _Float16* qkvl = qkvh + (size_t)BTOT * 3 * DD;    // fp16 lo (25.2 MB)
  float*    gates = (float*)(qkvl + (size_t)BTOT * 3 * DD);
  _Float16* x_hi = (_Float16*)(gates + (size_t)BTOT * HH);
  _Float16* x_lo = x_hi + (size_t)BTOT * DD;
  _Float16* Wqh  = x_lo + (size_t)BTOT * DD;
  _Float16* Wql  = Wqh + (size_t)DD * 3 * DD;
  _Float16* Woh  = Wql + (size_t)DD * 3 * DD;
  _Float16* Wol  = Woh + (size_t)DD * DD;
  // ypre hi/lo alias x_hi/x_lo (x split is dead after the qkv GEMM)
  _Float16* yhi = x_hi;
  _Float16* ylo = x_lo;

  split_f32<<<1024, 256, 0, stream>>>(x, x_hi, x_lo, BTOT * DD / 4);
  wsplit_t<<<dim3(3*DD/64, DD/64), 256, 0, stream>>>(Wqkv, Wqh, Wql, DD, 3*DD);
  wsplit_t<<<dim3(DD/64, DD/64), 256, 0, stream>>>(Wo, Woh, Wol, DD, DD);
  router_kernel<<<BTOT, 64, 0, stream>>>(x, Wr, gates);
  hgemm_split<true><<<dim3(3*DD/128, BTOT/128), 256, 0, stream>>>(
      x_hi, x_lo, Wqh, Wql, nullptr, qkvh, qkvl, BTOT, 3*DD, DD);
  attn_mfma<<<(TT/128)*BB*HH, 512, 0, stream>>>(qkvh, qkvl, gates, yhi, ylo);
  hgemm_split<false><<<dim3(DD/128, BTOT/128), 256, 0, stream>>>(
      yhi, ylo, Woh, Wol, out, nullptr, nullptr, BTOT, DD, DD);
}